// Round 6
// baseline (490.362 us; speedup 1.0000x reference)
//
#include <hip/hip_runtime.h>

typedef unsigned short u16;
typedef __bf16 bf16x8 __attribute__((ext_vector_type(8)));
typedef float f32x4 __attribute__((ext_vector_type(4)));

#define BB 4
#define TT 4096
#define HID 1024
#define NH 16
#define HD 64
#define BT (BB*TT)          // 16384 rows
#define NCH 256             // chunks over T (CLEN=16)
#define LOG_NCH 8
#define CLEN (TT/NCH)       // 16

__device__ __forceinline__ float bf2f(u16 u) {
    return __uint_as_float(((unsigned)u) << 16);
}
__device__ __forceinline__ u16 f2bf(float f) {
    unsigned u = __float_as_uint(f);
    unsigned r = 0x7FFFu + ((u >> 16) & 1u);
    return (u16)((u + r) >> 16);
}
__device__ __forceinline__ float phi(float x) {      // elu(x)+1
    return x > 0.f ? x + 1.f : __expf(x);
}
__device__ __forceinline__ float sigmoidf(float x) {
    return 1.f / (1.f + __expf(-x));
}
__device__ __forceinline__ float4 u4_to_f4(ushort4 u) {
    return make_float4(bf2f(u.x), bf2f(u.y), bf2f(u.z), bf2f(u.w));
}

// ---------------- fused fp32 -> bf16 convert (one launch for all 4 tensors) ----------
#define CN1 (BT*HID/4)          // x      : 4194304
#define CN2 (3*HID*HID/4)       // Wqkv   :  786432
#define CN3 (HID*HID/4)         // Wgate  :  262144
#define CN4 (HID*HID/4)         // Wout   :  262144
__global__ void convert_all(const float4* __restrict__ x,    const float4* __restrict__ wqkv,
                            const float4* __restrict__ wgate, const float4* __restrict__ wout,
                            ushort4* __restrict__ xb,    ushort4* __restrict__ wqkvb,
                            ushort4* __restrict__ wgateb, ushort4* __restrict__ woutb) {
    int i = blockIdx.x * 256 + threadIdx.x;
    const float4* src; ushort4* dst; int j;
    if (i < CN1)                 { src = x;     dst = xb;     j = i; }
    else if (i < CN1+CN2)        { src = wqkv;  dst = wqkvb;  j = i - CN1; }
    else if (i < CN1+CN2+CN3)    { src = wgate; dst = wgateb; j = i - CN1 - CN2; }
    else                         { src = wout;  dst = woutb;  j = i - CN1 - CN2 - CN3; }
    float4 f = src[j];
    ushort4 u;
    u.x = f2bf(f.x); u.y = f2bf(f.y); u.z = f2bf(f.z); u.w = f2bf(f.w);
    dst[j] = u;
}

// ---------------- 256x256 MFMA GEMM, 8-phase, 1-phase-ahead reg frags --------------
// C[M,N] = A[M,K] @ Bm[N,K]^T, bf16, 8 waves (2M x 4N), per-wave out 128x64.
// BK=64, LDS = 2x(A 256x64 + B 256x64) = 128 KiB double buffer (by K-tile parity).
// LDS-BW model: 24 ds_read_b128/wave/K-tile feeding 64 MFMA = 0.375 KB/MFMA ->
// under the 256 B/cy LDS ceiling at ~62% MfmaUtil (m201's measured number).
// Key difference vs failed r2: phase p's ds_reads feed phase p+1's MFMAs; NO asm
// lgkmcnt / sched_barrier (compiler emits counted lgkm waits itself — m141 lesson).
// Sync: counted s_waitcnt vmcnt(4) + s_barrier at even-phase ends only.
// Ledger (iter i: tile E=2i in buf0 phases 1-4, tile O=2i+1 in buf1 phases 5-8;
// one half-tile stage (2 global_load_lds/wave) per phase; confirm distance 4-5
// phases; WAR: every staged region's all-waves-read-complete barrier precedes it):
//  ph  stage                 reads(->regs for next phase)      MFMA (uses)
//  1   buf1.A1 (tile O)      bqB<-b0.B1, afY01<-b0.A1          E(0,0) afX*bqA
//  2   buf1.B1 (tile O)      afY23<-b0.A1                      E(0,1) afX*bqB   VM(4)
//  3   buf0.A0 (tile 2i+2)   afX01<-b1.A0                      E(1,0) afY*bqA
//  4   buf0.B0 (tile 2i+2)   afX23<-b1.A0, bqA<-b1.B0          E(1,1) afY*bqB   VM(4)
//  5   buf0.A1 (tile 2i+2)   bqB<-b1.B1, afY01<-b1.A1          O(0,0) afX*bqA
//  6   buf0.B1 (tile 2i+2)   afY23<-b1.A1                      O(0,1) afX*bqB   VM(4)
//  7   buf1.A0 (tile 2i+3)   afX01<-b0.A0                      O(1,0) afY*bqA
//  8   buf1.B0 (tile 2i+3)   afX23<-b0.A0, bqA<-b0.B0          O(1,1) afY*bqB   VM(4)
// Per-element k-accumulation order identical to the verified gemm_bt (bitwise).
// EPI 0: bf16 store. EPI 1: gate epilogue. EPI 2: fp32 store.
template<int EPI>
__global__ __launch_bounds__(512, 2)
void gemm8p(const u16* __restrict__ A, const u16* __restrict__ Bm,
            int M, int N, int K, void* __restrict__ Cout,
            const float* __restrict__ bg,
            const u16* __restrict__ attn,
            const u16* __restrict__ qkv)
{
    __shared__ u16 As[2][256 * 64];
    __shared__ u16 Bs[2][256 * 64];
    const int tid  = threadIdx.x;
    const int wave = tid >> 6;           // 0..7
    const int lane = tid & 63;
    const int r16  = lane & 15;
    const int m0 = blockIdx.y * 256;
    const int n0 = blockIdx.x * 256;
    const int wm = (wave & 1) * 128;
    const int wn = (wave >> 1) * 64;

    // ---- hoisted staging geometry (lean addressing; r3 spilled on recompute) ----
    const int q0 = wave * 2, q1 = wave * 2 + 1;
    const int rsub = lane >> 3;                    // row within 8-row group
    const int lcg  = (lane & 7) ^ (rsub & 7);      // pre-swizzled 16B chunk (verified pair)
    // LDS dest bases (u16 elems), + mq*64*64 / + nq*32*64 added as const
    const int ldsA0 = ((q0 >> 3) * 128 + (q0 & 7) * 8) * 64;
    const int ldsA1 = ((q1 >> 3) * 128 + (q1 & 7) * 8) * 64;
    const int ldsB0 = ((q0 >> 2) * 64  + (q0 & 3) * 8) * 64;
    const int ldsB1 = ((q1 >> 2) * 64  + (q1 & 3) * 8) * 64;
    // global element offsets (k0 / mq / nq added per call as uniform)
    const size_t gA0 = (size_t)(m0 + (q0 >> 3) * 128 + (q0 & 7) * 8 + rsub) * K + lcg * 8;
    const size_t gA1 = (size_t)(m0 + (q1 >> 3) * 128 + (q1 & 7) * 8 + rsub) * K + lcg * 8;
    const size_t gB0 = (size_t)(n0 + (q0 >> 2) * 64 + (q0 & 3) * 8 + rsub) * K + lcg * 8;
    const size_t gB1 = (size_t)(n0 + (q1 >> 2) * 64 + (q1 & 3) * 8 + rsub) * K + lcg * 8;
    // ds_read bases per k-slice (swizzled col), region offset folded as immediate
    const int p0 = ((lane >> 4)      ) ^ (r16 & 7);
    const int p1 = ((lane >> 4) + 4  ) ^ (r16 & 7);
    const int vA0 = (wm + r16) * 64 + p0 * 8;
    const int vA1 = (wm + r16) * 64 + p1 * 8;
    const int vB0 = (wn + r16) * 64 + p0 * 8;
    const int vB1 = (wn + r16) * 64 + p1 * 8;

    f32x4 acc[8][4];
    #pragma unroll
    for (int i = 0; i < 8; ++i)
        #pragma unroll
        for (int j = 0; j < 4; ++j)
            acc[i][j] = (f32x4){0.f, 0.f, 0.f, 0.f};

    bf16x8 afX[4][2], afY[4][2];   // A halves, rotating (current / next)
    bf16x8 bqA[2][2], bqB[2][2];   // B halves (nq=0 / nq=1)

#define STAGE_A(K0, BUF, MQ) do {                                              \
    __builtin_amdgcn_global_load_lds(                                          \
        (const __attribute__((address_space(1))) void*)(A + gA0 + (size_t)((MQ)*64) * K + (K0)), \
        (__attribute__((address_space(3))) void*)&As[BUF][ldsA0 + (MQ)*64*64], 16, 0, 0); \
    __builtin_amdgcn_global_load_lds(                                          \
        (const __attribute__((address_space(1))) void*)(A + gA1 + (size_t)((MQ)*64) * K + (K0)), \
        (__attribute__((address_space(3))) void*)&As[BUF][ldsA1 + (MQ)*64*64], 16, 0, 0); \
} while (0)
#define STAGE_B(K0, BUF, NQ) do {                                              \
    __builtin_amdgcn_global_load_lds(                                          \
        (const __attribute__((address_space(1))) void*)(Bm + gB0 + (size_t)((NQ)*32) * K + (K0)), \
        (__attribute__((address_space(3))) void*)&Bs[BUF][ldsB0 + (NQ)*32*64], 16, 0, 0); \
    __builtin_amdgcn_global_load_lds(                                          \
        (const __attribute__((address_space(1))) void*)(Bm + gB1 + (size_t)((NQ)*32) * K + (K0)), \
        (__attribute__((address_space(3))) void*)&Bs[BUF][ldsB1 + (NQ)*32*64], 16, 0, 0); \
} while (0)
#define RDA01(BUF, MQ, DST) do {                                               \
    DST[0][0] = *(const bf16x8*)&As[BUF][vA0 + ((MQ)*64 +  0) * 64];           \
    DST[0][1] = *(const bf16x8*)&As[BUF][vA1 + ((MQ)*64 +  0) * 64];           \
    DST[1][0] = *(const bf16x8*)&As[BUF][vA0 + ((MQ)*64 + 16) * 64];           \
    DST[1][1] = *(const bf16x8*)&As[BUF][vA1 + ((MQ)*64 + 16) * 64];           \
} while (0)
#define RDA23(BUF, MQ, DST) do {                                               \
    DST[2][0] = *(const bf16x8*)&As[BUF][vA0 + ((MQ)*64 + 32) * 64];           \
    DST[2][1] = *(const bf16x8*)&As[BUF][vA1 + ((MQ)*64 + 32) * 64];           \
    DST[3][0] = *(const bf16x8*)&As[BUF][vA0 + ((MQ)*64 + 48) * 64];           \
    DST[3][1] = *(const bf16x8*)&As[BUF][vA1 + ((MQ)*64 + 48) * 64];           \
} while (0)
#define RDB(BUF, NQ, DST) do {                                                 \
    DST[0][0] = *(const bf16x8*)&Bs[BUF][vB0 + ((NQ)*32 +  0) * 64];           \
    DST[0][1] = *(const bf16x8*)&Bs[BUF][vB1 + ((NQ)*32 +  0) * 64];           \
    DST[1][0] = *(const bf16x8*)&Bs[BUF][vB0 + ((NQ)*32 + 16) * 64];           \
    DST[1][1] = *(const bf16x8*)&Bs[BUF][vB1 + ((NQ)*32 + 16) * 64];           \
} while (0)
#define MFMAQ(MQ, NQ, AF, BQ) do {                                             \
    __builtin_amdgcn_s_setprio(1);                                             \
    _Pragma("unroll") for (int i_ = 0; i_ < 4; ++i_)                           \
    _Pragma("unroll") for (int j_ = 0; j_ < 2; ++j_)                           \
    _Pragma("unroll") for (int k_ = 0; k_ < 2; ++k_)                           \
        acc[(MQ)*4 + i_][(NQ)*2 + j_] = __builtin_amdgcn_mfma_f32_16x16x32_bf16( \
            AF[i_][k_], BQ[j_][k_], acc[(MQ)*4 + i_][(NQ)*2 + j_], 0, 0, 0);   \
    __builtin_amdgcn_s_setprio(0);                                             \
} while (0)
// counted vmcnt + barrier + hoist-fence (empty asm blocks LDS-read hoisting above
// the barrier; MFMAs may move freely — register-only, harmless)
#define VMBAR(NV) do {                                                         \
    asm volatile("s_waitcnt vmcnt(" #NV ")" ::: "memory");                     \
    __builtin_amdgcn_s_barrier();                                              \
    asm volatile("" ::: "memory");                                             \
} while (0)

    const int niter = K >> 7;            // 2 K-tiles per iteration (K=1024 -> 8)

    // prologue: buf0 complete (tile0) + buf1 A0,B0 (tile1); confirm buf0, 4 in flight
    STAGE_A(0, 0, 0); STAGE_B(0, 0, 0); STAGE_A(0, 0, 1); STAGE_B(0, 0, 1);
    STAGE_A(64, 1, 0); STAGE_B(64, 1, 0);
    VMBAR(4);
    RDA01(0, 0, afX); RDA23(0, 0, afX); RDB(0, 0, bqA);

    for (int i = 0; i < niter - 1; ++i) {
        const int kb = i * 128;
        STAGE_A(kb +  64, 1, 1); RDB(0, 1, bqB); RDA01(0, 1, afY); MFMAQ(0, 0, afX, bqA);
        STAGE_B(kb +  64, 1, 1); RDA23(0, 1, afY);                 MFMAQ(0, 1, afX, bqB); VMBAR(4);
        STAGE_A(kb + 128, 0, 0); RDA01(1, 0, afX);                 MFMAQ(1, 0, afY, bqA);
        STAGE_B(kb + 128, 0, 0); RDA23(1, 0, afX); RDB(1, 0, bqA); MFMAQ(1, 1, afY, bqB); VMBAR(4);
        STAGE_A(kb + 128, 0, 1); RDB(1, 1, bqB); RDA01(1, 1, afY); MFMAQ(0, 0, afX, bqA);
        STAGE_B(kb + 128, 0, 1); RDA23(1, 1, afY);                 MFMAQ(0, 1, afX, bqB); VMBAR(4);
        STAGE_A(kb + 192, 1, 0); RDA01(0, 0, afX);                 MFMAQ(1, 0, afY, bqA);
        STAGE_B(kb + 192, 1, 0); RDA23(0, 0, afX); RDB(0, 0, bqA); MFMAQ(1, 1, afY, bqB); VMBAR(4);
    }

    { // peeled last iteration: only the two stages still needed; tightened vmcnt
        const int kb = (niter - 1) * 128;
        STAGE_A(kb + 64, 1, 1); RDB(0, 1, bqB); RDA01(0, 1, afY);  MFMAQ(0, 0, afX, bqA);
        STAGE_B(kb + 64, 1, 1); RDA23(0, 1, afY);                  MFMAQ(0, 1, afX, bqB); VMBAR(4);
        RDA01(1, 0, afX);                                          MFMAQ(1, 0, afY, bqA);
        RDA23(1, 0, afX); RDB(1, 0, bqA);                          MFMAQ(1, 1, afY, bqB); VMBAR(0);
        RDB(1, 1, bqB); RDA01(1, 1, afY);                          MFMAQ(0, 0, afX, bqA);
        RDA23(1, 1, afY);                                          MFMAQ(0, 1, afX, bqB);
        MFMAQ(1, 0, afY, bqA);
        MFMAQ(1, 1, afY, bqB);
    }

    // epilogue: C/D layout col=lane&15, row=(lane>>4)*4+reg
    #pragma unroll
    for (int mi = 0; mi < 8; ++mi) {
        int rowb = m0 + wm + mi * 16 + (lane >> 4) * 4;
        #pragma unroll
        for (int nj = 0; nj < 4; ++nj) {
            int col = n0 + wn + nj * 16 + r16;
            #pragma unroll
            for (int r = 0; r < 4; ++r) {
                float v = acc[mi][nj][r];
                size_t row = (size_t)(rowb + r);
                if (EPI == 0) {
                    ((u16*)Cout)[row * N + col] = f2bf(v);
                } else if (EPI == 1) {
                    float g  = sigmoidf(v + bg[col]);
                    float at = bf2f(attn[row * HID + col]);
                    float vd = bf2f(qkv[row * (3 * HID) + 2 * HID + col]);
                    ((u16*)Cout)[row * HID + col] = f2bf(g * at + (1.f - g) * vd);
                } else {
                    ((float*)Cout)[row * N + col] = v;
                }
            }
        }
    }
#undef STAGE_A
#undef STAGE_B
#undef RDA01
#undef RDA23
#undef RDB
#undef MFMAQ
#undef VMBAR
}

// ---------------- scan pass A: per-chunk local finals (vectorized x4) --------------
__global__ void scan_finals(const u16* __restrict__ qkv, const float* __restrict__ decay_param,
                            float* __restrict__ ckv, float* __restrict__ cks) {
    int g  = blockIdx.x * 16 + (threadIdx.x >> 4);    // ((b*NH+h)*NCH + c)
    int sl = threadIdx.x & 15;
    int c = g & (NCH - 1);
    int h = (g >> LOG_NCH) & (NH - 1);
    int b = g >> (LOG_NCH + 4);
    float decay = sigmoidf(decay_param[h]);
    const u16* kp = qkv + (size_t)(b * TT + c * CLEN) * (3 * HID) + HID + h * HD + sl * 4;
    float4 skv = make_float4(0.f, 0.f, 0.f, 0.f);
    float4 sks = make_float4(0.f, 0.f, 0.f, 0.f);
    #pragma unroll
    for (int t = 0; t < CLEN; ++t) {
        float4 k = u4_to_f4(*(const ushort4*)kp);
        float4 v = u4_to_f4(*(const ushort4*)(kp + HID));
        k.x = phi(k.x); k.y = phi(k.y); k.z = phi(k.z); k.w = phi(k.w);
        skv.x = decay * skv.x + k.x * v.x;  skv.y = decay * skv.y + k.y * v.y;
        skv.z = decay * skv.z + k.z * v.z;  skv.w = decay * skv.w + k.w * v.w;
        sks.x = decay * sks.x + k.x;        sks.y = decay * sks.y + k.y;
        sks.z = decay * sks.z + k.z;        sks.w = decay * sks.w + k.w;
        kp += 3 * HID;
    }
    *(float4*)(ckv + (size_t)g * 64 + sl * 4) = skv;
    *(float4*)(cks + (size_t)g * 64 + sl * 4) = sks;
}

// ---------------- scan pass B: cross-chunk exclusive prefix (in place) -------------
__global__ void scan_prefix(float* __restrict__ ckv, float* __restrict__ cks,
                            const float* __restrict__ decay_param) {
    int bh = blockIdx.x;
    int h  = bh & (NH - 1);
    int lane = threadIdx.x;
    float decay = sigmoidf(decay_param[h]);
    float dC = powf(decay, (float)CLEN);
    float* pkv = ckv + (size_t)bh * NCH * 64 + lane;
    float* pks = cks + (size_t)bh * NCH * 64 + lane;
    float fkv = 0.f, fks = 0.f;
    for (int c = 0; c < NCH; ++c) {
        float lkv = pkv[c * 64], lks = pks[c * 64];
        pkv[c * 64] = fkv; pks[c * 64] = fks;
        fkv = fkv * dC + lkv;
        fks = fks * dC + lks;
    }
}

// ---------------- scan pass C: apply with init, den-reduce, write attn (x4) --------
__global__ void scan_apply(const u16* __restrict__ qkv, const float* __restrict__ decay_param,
                           const float* __restrict__ ckv, const float* __restrict__ cks,
                           u16* __restrict__ attn) {
    int g  = blockIdx.x * 16 + (threadIdx.x >> 4);
    int sl = threadIdx.x & 15;
    int c = g & (NCH - 1);
    int h = (g >> LOG_NCH) & (NH - 1);
    int b = g >> (LOG_NCH + 4);
    float decay = sigmoidf(decay_param[h]);
    float4 skv = *(const float4*)(ckv + (size_t)g * 64 + sl * 4);
    float4 sks = *(const float4*)(cks + (size_t)g * 64 + sl * 4);
    const u16* qp = qkv + (size_t)(b * TT + c * CLEN) * (3 * HID) + h * HD + sl * 4;
    u16* op = attn + (size_t)(b * TT + c * CLEN) * HID + h * HD + sl * 4;
    #pragma unroll
    for (int t = 0; t < CLEN; ++t) {
        float4 q = u4_to_f4(*(const ushort4*)qp);
        float4 k = u4_to_f4(*(const ushort4*)(qp + HID));
        float4 v = u4_to_f4(*(const ushort4*)(qp + 2 * HID));
        q.x = phi(q.x); q.y = phi(q.y); q.z = phi(q.z); q.w = phi(q.w);
        k.x = phi(k.x); k.y = phi(k.y); k.z = phi(k.z); k.w = phi(k.w);
        skv.x = decay * skv.x + k.x * v.x;  skv.y = decay * skv.y + k.y * v.y;
        skv.z = decay * skv.z + k.z * v.z;  skv.w = decay * skv.w + k.w * v.w;
        sks.x = decay * sks.x + k.x;        sks.y = decay * sks.y + k.y;
        sks.z = decay * sks.z + k.z;        sks.w = decay * sks.w + k.w;
        float s = q.x * sks.x + q.y * sks.y + q.z * sks.z + q.w * sks.w;
        s += __shfl_xor(s, 8);
        s += __shfl_xor(s, 4);
        s += __shfl_xor(s, 2);
        s += __shfl_xor(s, 1);
        float inv = 1.f / fmaxf(s, 1e-6f);
        ushort4 o;
        o.x = f2bf(q.x * skv.x * inv); o.y = f2bf(q.y * skv.y * inv);
        o.z = f2bf(q.z * skv.z * inv); o.w = f2bf(q.w * skv.w * inv);
        *(ushort4*)op = o;
        qp += 3 * HID;
        op += HID;
    }
}

extern "C" void kernel_launch(void* const* d_in, const int* in_sizes, int n_in,
                              void* d_out, int out_size, void* d_ws, size_t ws_size,
                              hipStream_t stream) {
    const float* x     = (const float*)d_in[0];   // [4,4096,1024]
    const float* Wqkv  = (const float*)d_in[1];   // [3072,1024]
    const float* Wout  = (const float*)d_in[2];   // [1024,1024]
    const float* Wgate = (const float*)d_in[3];   // [1024,1024]
    const float* bgate = (const float*)d_in[4];   // [1024]
    const float* decay = (const float*)d_in[5];   // [16]

    // workspace layout (bf16 elements)
    u16* xb     = (u16*)d_ws;                                 // 16384*1024 (aliased as attn later)
    u16* wqkvb  = xb    + (size_t)BT * HID;                   // 3072*1024
    u16* wgateb = wqkvb + (size_t)3 * HID * HID;              // 1024*1024
    u16* woutb  = wgateb + (size_t)HID * HID;                 // 1024*1024
    u16* qkvb   = woutb + (size_t)HID * HID;                  // 16384*3072
    u16* out2b  = qkvb  + (size_t)BT * 3 * HID;               // 16384*1024
    // ckv/cks live in the out2b region (dead until GEMM2; scan_apply reads them
    // before GEMM2 writes out2b)
    float* ckv  = (float*)out2b;                              // 4*16*256*64 fp32
    float* cks  = ckv + (size_t)BB * NH * NCH * HD;
    u16* attnb  = xb;  // alias: x dead after GEMM1

    // fused converts (one launch)
    convert_all<<<(CN1 + CN2 + CN3 + CN4) / 256, 256, 0, stream>>>(
        (const float4*)x, (const float4*)Wqkv, (const float4*)Wgate, (const float4*)Wout,
        (ushort4*)xb, (ushort4*)wqkvb, (ushort4*)wgateb, (ushort4*)woutb);

    // GEMM1: qkv = x @ Wqkv^T  -> bf16 [16384,3072]  (8-phase 256^2)
    gemm8p<0><<<dim3(3 * HID / 256, BT / 256), 512, 0, stream>>>(
        xb, wqkvb, BT, 3 * HID, HID, qkvb, nullptr, nullptr, nullptr);

    // decay scans -> attn bf16 [16384,1024]
    scan_finals<<<BB * NH * NCH / 16, 256, 0, stream>>>(qkvb, decay, ckv, cks);
    scan_prefix<<<BB * NH, 64, 0, stream>>>(ckv, cks, decay);
    scan_apply<<<BB * NH * NCH / 16, 256, 0, stream>>>(qkvb, decay, ckv, cks, attnb);

    // GEMM2: gate + blend -> out2 bf16 [16384,1024]  (256 blocks = 1/CU exactly)
    gemm8p<1><<<dim3(HID / 256, BT / 256), 512, 0, stream>>>(
        attnb, wgateb, BT, HID, HID, out2b, bgate, attnb, qkvb);

    // GEMM3: final projection -> fp32 d_out
    gemm8p<2><<<dim3(HID / 256, BT / 256), 512, 0, stream>>>(
        out2b, woutb, BT, HID, HID, d_out, nullptr, nullptr, nullptr);
}

// Round 7
// 376.282 us; speedup vs baseline: 1.3032x; 1.3032x over previous
//
#include <hip/hip_runtime.h>

typedef unsigned short u16;
typedef __bf16 bf16x8 __attribute__((ext_vector_type(8)));
typedef float f32x4 __attribute__((ext_vector_type(4)));

#define BB 4
#define TT 4096
#define HID 1024
#define NH 16
#define HD 64
#define BT (BB*TT)          // 16384 rows
#define NCH 128             // chunks over T
#define LOG_NCH 7
#define CLEN (TT/NCH)       // 32

__device__ __forceinline__ float bf2f(u16 u) {
    return __uint_as_float(((unsigned)u) << 16);
}
__device__ __forceinline__ u16 f2bf(float f) {
    unsigned u = __float_as_uint(f);
    unsigned r = 0x7FFFu + ((u >> 16) & 1u);
    return (u16)((u + r) >> 16);
}
__device__ __forceinline__ float phi(float x) {      // elu(x)+1
    return x > 0.f ? x + 1.f : __expf(x);
}
__device__ __forceinline__ float sigmoidf(float x) {
    return 1.f / (1.f + __expf(-x));
}
__device__ __forceinline__ float4 u4_to_f4(ushort4 u) {
    return make_float4(bf2f(u.x), bf2f(u.y), bf2f(u.z), bf2f(u.w));
}

// XCD-aware bijective block swizzle (T1). Requires nwg % 8 == 0 (both GEMM grids
// qualify: 3072 and 256). Dispatch round-robins linear block id across the 8 XCDs;
// remapping work = (lin&7)*cpx + (lin>>3) gives each XCD a CONTIGUOUS chunk of
// output tiles -> shared A row-panels hit in one XCD's L2 instead of 8.
__device__ __forceinline__ void xcd_swizzle(int& bx, int& by) {
    const unsigned nwg = gridDim.x * gridDim.y;
    const unsigned lin = blockIdx.y * gridDim.x + blockIdx.x;
    const unsigned cpx = nwg >> 3;
    const unsigned swz = (lin & 7u) * cpx + (lin >> 3);
    bx = swz % gridDim.x;
    by = swz / gridDim.x;
}

// ---------------- fused fp32 -> bf16 convert (one launch for all 4 tensors) ----------
#define CN1 (BT*HID/4)          // x      : 4194304
#define CN2 (3*HID*HID/4)       // Wqkv   :  786432
#define CN3 (HID*HID/4)         // Wgate  :  262144
#define CN4 (HID*HID/4)         // Wout   :  262144
__global__ void convert_all(const float4* __restrict__ x,    const float4* __restrict__ wqkv,
                            const float4* __restrict__ wgate, const float4* __restrict__ wout,
                            ushort4* __restrict__ xb,    ushort4* __restrict__ wqkvb,
                            ushort4* __restrict__ wgateb, ushort4* __restrict__ woutb) {
    int i = blockIdx.x * 256 + threadIdx.x;
    const float4* src; ushort4* dst; int j;
    if (i < CN1)                 { src = x;     dst = xb;     j = i; }
    else if (i < CN1+CN2)        { src = wqkv;  dst = wqkvb;  j = i - CN1; }
    else if (i < CN1+CN2+CN3)    { src = wgate; dst = wgateb; j = i - CN1 - CN2; }
    else                         { src = wout;  dst = woutb;  j = i - CN1 - CN2 - CN3; }
    float4 f = src[j];
    ushort4 u;
    u.x = f2bf(f.x); u.y = f2bf(f.y); u.z = f2bf(f.z); u.w = f2bf(f.w);
    dst[j] = u;
}

// ---------------- MFMA GEMM: C[M,N] = A[M,K] @ W[N,K]^T (both K-major bf16) ---------
// 128x128 tile, BK=64, 4 waves (each 64x64 via 4x4 of 16x16x32 mfma).
// LDS XOR swizzle: physical 16B-chunk = logical chunk ^ (row&7); measured 0 bank
// conflicts, MfmaUtil 39-42%, ~870 TF. This is the measured GEMM1 floor for this
// harness: 256^2 8-phase variants (r1/r2/r3/r6) all lost — the unified VGPR file
// gives only ~128 arch VGPRs beside the 128-reg accumulator, so phase-ahead frag
// buffers spill (WRITE_SIZE 98->260 MB signature, r6).
template<int EPI>
__global__ __launch_bounds__(256)
void gemm_bt(const u16* __restrict__ A, const u16* __restrict__ Bm,
             int M, int N, int K, void* __restrict__ Cout,
             const float* __restrict__ bg,
             const u16* __restrict__ attn,
             const u16* __restrict__ qkv)
{
    __shared__ u16 As[128 * 64];
    __shared__ u16 Bs[128 * 64];
    const int tid  = threadIdx.x;
    const int wave = tid >> 6;
    const int lane = tid & 63;
    int bx, by;
    xcd_swizzle(bx, by);
    const int m0 = by * 128;
    const int n0 = bx * 128;
    const int mw = (wave & 1) * 64;
    const int nw = (wave >> 1) * 64;
    const int r16 = lane & 15;

    f32x4 acc[4][4];
    #pragma unroll
    for (int i = 0; i < 4; ++i)
        #pragma unroll
        for (int j = 0; j < 4; ++j)
            acc[i][j] = (f32x4){0.f, 0.f, 0.f, 0.f};

    for (int k0 = 0; k0 < K; k0 += 64) {
        #pragma unroll
        for (int i = 0; i < 4; ++i) {
            int s   = i * 4 + wave;          // segment 0..15 (wave-uniform)
            int idx = s * 64 + lane;         // linear 16B-chunk index
            int pr  = idx >> 3;
            int pc  = idx & 7;
            int lc  = pc ^ (pr & 7);         // XOR swizzle
            const u16* gA = A  + (size_t)(m0 + pr) * K + k0 + lc * 8;
            const u16* gB = Bm + (size_t)(n0 + pr) * K + k0 + lc * 8;
            __builtin_amdgcn_global_load_lds(
                (const __attribute__((address_space(1))) void*)gA,
                (__attribute__((address_space(3))) void*)&As[s * 512], 16, 0, 0);
            __builtin_amdgcn_global_load_lds(
                (const __attribute__((address_space(1))) void*)gB,
                (__attribute__((address_space(3))) void*)&Bs[s * 512], 16, 0, 0);
        }
        __syncthreads();
        #pragma unroll
        for (int s2 = 0; s2 < 2; ++s2) {
            const int lcq = s2 * 4 + (lane >> 4);
            const int pcq = lcq ^ (r16 & 7);
            bf16x8 af[4], bq[4];
            #pragma unroll
            for (int i = 0; i < 4; ++i)
                af[i] = *(const bf16x8*)&As[(mw + i * 16 + r16) * 64 + pcq * 8];
            #pragma unroll
            for (int j = 0; j < 4; ++j)
                bq[j] = *(const bf16x8*)&Bs[(nw + j * 16 + r16) * 64 + pcq * 8];
            #pragma unroll
            for (int i = 0; i < 4; ++i)
                #pragma unroll
                for (int j = 0; j < 4; ++j)
                    acc[i][j] = __builtin_amdgcn_mfma_f32_16x16x32_bf16(af[i], bq[j], acc[i][j], 0, 0, 0);
        }
        __syncthreads();
    }

    // epilogue: C/D layout col=lane&15, row=(lane>>4)*4+reg
    #pragma unroll
    for (int i = 0; i < 4; ++i) {
        int rowb = m0 + mw + i * 16 + (lane >> 4) * 4;
        #pragma unroll
        for (int j = 0; j < 4; ++j) {
            int col = n0 + nw + j * 16 + r16;
            #pragma unroll
            for (int r = 0; r < 4; ++r) {
                float v = acc[i][j][r];
                size_t row = (size_t)(rowb + r);
                if (EPI == 0) {
                    ((u16*)Cout)[row * N + col] = f2bf(v);
                } else if (EPI == 1) {
                    float g  = sigmoidf(v + bg[col]);
                    float at = bf2f(attn[row * HID + col]);
                    float vd = bf2f(qkv[row * (3 * HID) + 2 * HID + col]);
                    ((u16*)Cout)[row * HID + col] = f2bf(g * at + (1.f - g) * vd);
                } else {
                    ((float*)Cout)[row * N + col] = v;
                }
            }
        }
    }
}

// ---------------- 256x256 MFMA GEMM, coarse counted-vmcnt pipeline -----------------
// r1-measured best structure for the N=1024 GEMMs (grid = 256 blocks = 1/CU).
// 8 waves (2M x 4N), per-wave 128x64 out, BK=64, 128 KiB LDS double buffer.
// Per K-tile t: COMPUTE(buf[t&1]) -> s_barrier -> STAGE(t+2) -> vmcnt(8) -> s_barrier.
template<int EPI>
__global__ __launch_bounds__(512, 2)
void gemm256(const u16* __restrict__ A, const u16* __restrict__ Bm,
             int M, int N, int K, void* __restrict__ Cout,
             const float* __restrict__ bg,
             const u16* __restrict__ attn,
             const u16* __restrict__ qkv)
{
    __shared__ u16 As[2][256 * 64];
    __shared__ u16 Bs[2][256 * 64];
    const int tid  = threadIdx.x;
    const int wave = tid >> 6;           // 0..7
    const int lane = tid & 63;
    const int r16  = lane & 15;
    int bx, by;
    xcd_swizzle(bx, by);
    const int m0 = by * 256;
    const int n0 = bx * 256;
    const int wm = (wave & 1) * 128;     // wave row offset
    const int wn = (wave >> 1) * 64;     // wave col offset

    f32x4 acc[8][4];
    #pragma unroll
    for (int i = 0; i < 8; ++i)
        #pragma unroll
        for (int j = 0; j < 4; ++j)
            acc[i][j] = (f32x4){0.f, 0.f, 0.f, 0.f};

    // stage one K-tile (A 256x64 + B 256x64) into buffer buf: 8 loads/thread
    auto STAGE = [&](int k0, int buf) {
        #pragma unroll
        for (int j = 0; j < 4; ++j) {
            int s   = j * 8 + wave;          // segment 0..31 (8 rows each), wave-uniform
            int idx = s * 64 + lane;         // linear 16B-chunk index
            int pr  = idx >> 3;              // row 0..255
            int lc  = (idx & 7) ^ (pr & 7);  // XOR swizzle on global source
            const u16* gA = A  + (size_t)(m0 + pr) * K + k0 + lc * 8;
            const u16* gB = Bm + (size_t)(n0 + pr) * K + k0 + lc * 8;
            __builtin_amdgcn_global_load_lds(
                (const __attribute__((address_space(1))) void*)gA,
                (__attribute__((address_space(3))) void*)&As[buf][s * 512], 16, 0, 0);
            __builtin_amdgcn_global_load_lds(
                (const __attribute__((address_space(1))) void*)gB,
                (__attribute__((address_space(3))) void*)&Bs[buf][s * 512], 16, 0, 0);
        }
    };

    // one K-tile of compute from buffer buf
    auto COMPUTE = [&](int buf) {
        bf16x8 bq[4][2];
        #pragma unroll
        for (int j = 0; j < 4; ++j) {
            #pragma unroll
            for (int ks = 0; ks < 2; ++ks) {
                int lcq = ks * 4 + (lane >> 4);
                int pcq = lcq ^ (r16 & 7);
                bq[j][ks] = *(const bf16x8*)&Bs[buf][(wn + j * 16 + r16) * 64 + pcq * 8];
            }
        }
        #pragma unroll
        for (int rh = 0; rh < 2; ++rh) {
            bf16x8 af[4][2];
            #pragma unroll
            for (int i = 0; i < 4; ++i) {
                #pragma unroll
                for (int ks = 0; ks < 2; ++ks) {
                    int lcq = ks * 4 + (lane >> 4);
                    int pcq = lcq ^ (r16 & 7);
                    af[i][ks] = *(const bf16x8*)&As[buf][(wm + rh * 64 + i * 16 + r16) * 64 + pcq * 8];
                }
            }
            __builtin_amdgcn_s_setprio(1);
            #pragma unroll
            for (int i = 0; i < 4; ++i)
                #pragma unroll
                for (int j = 0; j < 4; ++j)
                    #pragma unroll
                    for (int ks = 0; ks < 2; ++ks)
                        acc[rh * 4 + i][j] = __builtin_amdgcn_mfma_f32_16x16x32_bf16(
                            af[i][ks], bq[j][ks], acc[rh * 4 + i][j], 0, 0, 0);
            __builtin_amdgcn_s_setprio(0);
        }
    };

    const int nt = K >> 6;               // K-tiles
    STAGE(0, 0);
    STAGE(64, 1);
    asm volatile("s_waitcnt vmcnt(8)" ::: "memory");   // tile 0 landed, tile 1 in flight
    __builtin_amdgcn_sched_barrier(0);
    __builtin_amdgcn_s_barrier();
    __builtin_amdgcn_sched_barrier(0);

    for (int t = 0; t < nt; ++t) {
        COMPUTE(t & 1);
        if (t + 1 < nt) {
            __builtin_amdgcn_sched_barrier(0);
            __builtin_amdgcn_s_barrier();            // reads of buf[t&1] complete
            __builtin_amdgcn_sched_barrier(0);
            if (t + 2 < nt) {
                STAGE((t + 2) << 6, t & 1);          // refill freed buffer
                asm volatile("s_waitcnt vmcnt(8)" ::: "memory");  // tile t+1 landed
            } else {
                asm volatile("s_waitcnt vmcnt(0)" ::: "memory");  // final drain
            }
            __builtin_amdgcn_sched_barrier(0);
            __builtin_amdgcn_s_barrier();            // all waves' t+1 loads visible
            __builtin_amdgcn_sched_barrier(0);
        }
    }

    // epilogue: C/D layout col=lane&15, row=(lane>>4)*4+reg
    #pragma unroll
    for (int rh = 0; rh < 2; ++rh) {
        #pragma unroll
        for (int i = 0; i < 4; ++i) {
            int rowb = m0 + wm + rh * 64 + i * 16 + (lane >> 4) * 4;
            #pragma unroll
            for (int j = 0; j < 4; ++j) {
                int col = n0 + wn + j * 16 + r16;
                #pragma unroll
                for (int r = 0; r < 4; ++r) {
                    float v = acc[rh * 4 + i][j][r];
                    size_t row = (size_t)(rowb + r);
                    if (EPI == 0) {
                        ((u16*)Cout)[row * N + col] = f2bf(v);
                    } else if (EPI == 1) {
                        float g  = sigmoidf(v + bg[col]);
                        float at = bf2f(attn[row * HID + col]);
                        float vd = bf2f(qkv[row * (3 * HID) + 2 * HID + col]);
                        ((u16*)Cout)[row * HID + col] = f2bf(g * at + (1.f - g) * vd);
                    } else {
                        ((float*)Cout)[row * N + col] = v;
                    }
                }
            }
        }
    }
}

// ---------------- scan pass A: per-chunk local finals (vectorized x4) --------------
// 16-lane group -> one (b,h,chunk); sub-lane sl handles d = sl*4..sl*4+3
__global__ void scan_finals(const u16* __restrict__ qkv, const float* __restrict__ decay_param,
                            float* __restrict__ ckv, float* __restrict__ cks) {
    int g  = blockIdx.x * 16 + (threadIdx.x >> 4);    // ((b*NH+h)*NCH + c)
    int sl = threadIdx.x & 15;
    int c = g & (NCH - 1);
    int h = (g >> LOG_NCH) & (NH - 1);
    int b = g >> (LOG_NCH + 4);
    float decay = sigmoidf(decay_param[h]);
    const u16* kp = qkv + (size_t)(b * TT + c * CLEN) * (3 * HID) + HID + h * HD + sl * 4;
    float4 skv = make_float4(0.f, 0.f, 0.f, 0.f);
    float4 sks = make_float4(0.f, 0.f, 0.f, 0.f);
    for (int t = 0; t < CLEN; ++t) {
        float4 k = u4_to_f4(*(const ushort4*)kp);
        float4 v = u4_to_f4(*(const ushort4*)(kp + HID));
        k.x = phi(k.x); k.y = phi(k.y); k.z = phi(k.z); k.w = phi(k.w);
        skv.x = decay * skv.x + k.x * v.x;  skv.y = decay * skv.y + k.y * v.y;
        skv.z = decay * skv.z + k.z * v.z;  skv.w = decay * skv.w + k.w * v.w;
        sks.x = decay * sks.x + k.x;        sks.y = decay * sks.y + k.y;
        sks.z = decay * sks.z + k.z;        sks.w = decay * sks.w + k.w;
        kp += 3 * HID;
    }
    *(float4*)(ckv + (size_t)g * 64 + sl * 4) = skv;
    *(float4*)(cks + (size_t)g * 64 + sl * 4) = sks;
}

// ---------------- scan pass B: cross-chunk exclusive prefix (in place) -------------
__global__ void scan_prefix(float* __restrict__ ckv, float* __restrict__ cks,
                            const float* __restrict__ decay_param) {
    int bh = blockIdx.x;
    int h  = bh & (NH - 1);
    int lane = threadIdx.x;
    float decay = sigmoidf(decay_param[h]);
    float dC = powf(decay, (float)CLEN);
    float* pkv = ckv + (size_t)bh * NCH * 64 + lane;
    float* pks = cks + (size_t)bh * NCH * 64 + lane;
    float fkv = 0.f, fks = 0.f;
    for (int c = 0; c < NCH; ++c) {
        float lkv = pkv[c * 64], lks = pks[c * 64];
        pkv[c * 64] = fkv; pks[c * 64] = fks;
        fkv = fkv * dC + lkv;
        fks = fks * dC + lks;
    }
}

// ---------------- scan pass C: apply with init, den-reduce, write attn (x4) --------
__global__ void scan_apply(const u16* __restrict__ qkv, const float* __restrict__ decay_param,
                           const float* __restrict__ ckv, const float* __restrict__ cks,
                           u16* __restrict__ attn) {
    int g  = blockIdx.x * 16 + (threadIdx.x >> 4);
    int sl = threadIdx.x & 15;
    int c = g & (NCH - 1);
    int h = (g >> LOG_NCH) & (NH - 1);
    int b = g >> (LOG_NCH + 4);
    float decay = sigmoidf(decay_param[h]);
    float4 skv = *(const float4*)(ckv + (size_t)g * 64 + sl * 4);
    float4 sks = *(const float4*)(cks + (size_t)g * 64 + sl * 4);
    const u16* qp = qkv + (size_t)(b * TT + c * CLEN) * (3 * HID) + h * HD + sl * 4;
    u16* op = attn + (size_t)(b * TT + c * CLEN) * HID + h * HD + sl * 4;
    for (int t = 0; t < CLEN; ++t) {
        float4 q = u4_to_f4(*(const ushort4*)qp);
        float4 k = u4_to_f4(*(const ushort4*)(qp + HID));
        float4 v = u4_to_f4(*(const ushort4*)(qp + 2 * HID));
        q.x = phi(q.x); q.y = phi(q.y); q.z = phi(q.z); q.w = phi(q.w);
        k.x = phi(k.x); k.y = phi(k.y); k.z = phi(k.z); k.w = phi(k.w);
        skv.x = decay * skv.x + k.x * v.x;  skv.y = decay * skv.y + k.y * v.y;
        skv.z = decay * skv.z + k.z * v.z;  skv.w = decay * skv.w + k.w * v.w;
        sks.x = decay * sks.x + k.x;        sks.y = decay * sks.y + k.y;
        sks.z = decay * sks.z + k.z;        sks.w = decay * sks.w + k.w;
        float s = q.x * sks.x + q.y * sks.y + q.z * sks.z + q.w * sks.w;
        s += __shfl_xor(s, 8);
        s += __shfl_xor(s, 4);
        s += __shfl_xor(s, 2);
        s += __shfl_xor(s, 1);
        float inv = 1.f / fmaxf(s, 1e-6f);
        ushort4 o;
        o.x = f2bf(q.x * skv.x * inv); o.y = f2bf(q.y * skv.y * inv);
        o.z = f2bf(q.z * skv.z * inv); o.w = f2bf(q.w * skv.w * inv);
        *(ushort4*)op = o;
        qp += 3 * HID;
        op += HID;
    }
}

extern "C" void kernel_launch(void* const* d_in, const int* in_sizes, int n_in,
                              void* d_out, int out_size, void* d_ws, size_t ws_size,
                              hipStream_t stream) {
    const float* x     = (const float*)d_in[0];   // [4,4096,1024]
    const float* Wqkv  = (const float*)d_in[1];   // [3072,1024]
    const float* Wout  = (const float*)d_in[2];   // [1024,1024]
    const float* Wgate = (const float*)d_in[3];   // [1024,1024]
    const float* bgate = (const float*)d_in[4];   // [1024]
    const float* decay = (const float*)d_in[5];   // [16]

    // workspace layout (bf16 elements)
    u16* xb     = (u16*)d_ws;                                 // 16384*1024 (aliased as attn later)
    u16* wqkvb  = xb    + (size_t)BT * HID;                   // 3072*1024
    u16* wgateb = wqkvb + (size_t)3 * HID * HID;              // 1024*1024
    u16* woutb  = wgateb + (size_t)HID * HID;                 // 1024*1024
    u16* qkvb   = woutb + (size_t)HID * HID;                  // 16384*3072
    u16* out2b  = qkvb  + (size_t)BT * 3 * HID;               // 16384*1024
    float* ckv  = (float*)(out2b + (size_t)BT * HID);         // 4*16*128*64
    float* cks  = ckv + (size_t)BB * NH * NCH * HD;
    u16* attnb  = xb;  // alias: x dead after GEMM1

    // fused converts (one launch)
    convert_all<<<(CN1 + CN2 + CN3 + CN4) / 256, 256, 0, stream>>>(
        (const float4*)x, (const float4*)Wqkv, (const float4*)Wgate, (const float4*)Wout,
        (ushort4*)xb, (ushort4*)wqkvb, (ushort4*)wgateb, (ushort4*)woutb);

    // GEMM1: qkv = x @ Wqkv^T  -> bf16 [16384,3072]  (128^2 tile + XCD swizzle)
    gemm_bt<0><<<dim3(3 * HID / 128, BT / 128), 256, 0, stream>>>(
        xb, wqkvb, BT, 3 * HID, HID, qkvb, nullptr, nullptr, nullptr);

    // decay scans -> attn bf16 [16384,1024]
    scan_finals<<<BB * NH * NCH / 16, 256, 0, stream>>>(qkvb, decay, ckv, cks);
    scan_prefix<<<BB * NH, 64, 0, stream>>>(ckv, cks, decay);
    scan_apply<<<BB * NH * NCH / 16, 256, 0, stream>>>(qkvb, decay, ckv, cks, attnb);

    // GEMM2: gate + blend -> out2 bf16 [16384,1024]  (256^2 coarse + XCD swizzle)
    gemm256<1><<<dim3(HID / 256, BT / 256), 512, 0, stream>>>(
        attnb, wgateb, BT, HID, HID, out2b, bgate, attnb, qkvb);

    // GEMM3: final projection -> fp32 d_out  (256^2 coarse + XCD swizzle)
    gemm256<2><<<dim3(HID / 256, BT / 256), 512, 0, stream>>>(
        out2b, woutb, BT, HID, HID, d_out, nullptr, nullptr, nullptr);
}